// Round 17
// baseline (143.153 us; speedup 1.0000x reference)
//
#include <hip/hip_runtime.h>
#include <hip/hip_bf16.h>
#include <math.h>

typedef short bhalf8 __attribute__((ext_vector_type(8)));
typedef float floatx4 __attribute__((ext_vector_type(4)));

__device__ __forceinline__ float sigmoidf_(float x) { return 1.0f / (1.0f + __expf(-x)); }

__device__ __forceinline__ unsigned short f2bf(float f) {
    unsigned int u = __builtin_bit_cast(unsigned int, f);
    u += 0x7FFFu + ((u >> 16) & 1u);
    return (unsigned short)(u >> 16);
}
__device__ __forceinline__ float bf2f(unsigned short h) {
    unsigned int u = ((unsigned int)h) << 16;
    return __builtin_bit_cast(float, u);
}

__device__ __forceinline__ floatx4 mfma16(bhalf8 a, bhalf8 b, floatx4 c) {
    return __builtin_amdgcn_mfma_f32_16x16x32_bf16(a, b, c, 0, 0, 0);
}

// async global->LDS, 16B/lane: LDS dest = wave-uniform base + lane*16.
__device__ __forceinline__ void gl_lds16(const unsigned short* g, unsigned short* l) {
    __builtin_amdgcn_global_load_lds(
        (const __attribute__((address_space(1))) void*)g,
        (__attribute__((address_space(3))) void*)l, 16, 0, 0);
}

// ---------------------------------------------------------------------------
// pack helpers: f32 [K][N] -> bf16 B-fragment-linear tiles.
// ---------------------------------------------------------------------------
__device__ __forceinline__ void pack_generic(
    int b, int tid, const float* __restrict__ W0, const float* __restrict__ W1,
    int split, int N, int BN, unsigned short* __restrict__ out)
{
    int t = b * 256 + tid;
    int j = t & 7;
    int lane = (t >> 3) & 63;
    int FT = BN >> 4;
    int f = (t >> 9) % FT;
    int rest = t / (512 * FT);
    int NT = N / BN;
    int nt = rest % NT;
    int kt = rest / NT;
    int k = kt * 32 + (lane >> 4) * 8 + j;
    int n = nt * BN + f * 16 + (lane & 15);
    float v = (n < split) ? W0[(size_t)k * split + n]
                          : W1[(size_t)k * (N - split) + (n - split)];
    out[t] = f2bf(v);
}

// combined GRU pack: Wcat[768][768] = [W_i ; W_h]
__device__ __forceinline__ void pack_gru_(
    int b, int tid, const float* __restrict__ Wi, const float* __restrict__ Wh,
    unsigned short* __restrict__ out)
{
    int t = b * 256 + tid;
    int j = t & 7;
    int lane = (t >> 3) & 63;
    int f = (t >> 9) & 3;
    int q = t >> 11;
    int g = q % 3;
    int p = q / 3;
    int dt = p & 3;
    int kt = p >> 2;
    int k = kt * 32 + (lane >> 4) * 8 + j;
    int n = g * 256 + dt * 64 + f * 16 + (lane & 15);
    float v = (k < 512) ? Wi[(size_t)k * 768 + n] : Wh[(size_t)(k - 512) * 768 + n];
    out[t] = f2bf(v);
}

// P0: all weight packs + embedding gather in ONE launch (7936 blocks)
__global__ __launch_bounds__(256) void pack_all(
    const float* __restrict__ W_ein, const float* __restrict__ W_eout,
    const float* __restrict__ Wi, const float* __restrict__ Wh,
    const float* __restrict__ W2, const float* __restrict__ Wn1,
    const float* __restrict__ Wn2,
    const int* __restrict__ items, const float* __restrict__ emb,
    unsigned short* __restrict__ Wio_pk, unsigned short* __restrict__ Wg_pk,
    unsigned short* __restrict__ W2pk, unsigned short* __restrict__ Wn1pk,
    unsigned short* __restrict__ Wn2pk, unsigned short* __restrict__ hidden_pk)
{
    int bx = blockIdx.x;
    int tid = threadIdx.x;
    if (bx < 512)       { pack_generic(bx,        tid, W_ein, W_eout, 256, 512, 128, Wio_pk); return; }
    if (bx < 2816)      { pack_gru_   (bx - 512,  tid, Wi, Wh, Wg_pk); return; }
    if (bx < 3072)      { pack_generic(bx - 2816, tid, W2,  W2,  256, 256, 256, W2pk); return; }
    if (bx < 3584)      { pack_generic(bx - 3072, tid, Wn1, Wn1, 256, 256, 256, Wn1pk); return; }
    if (bx < 3840)      { pack_generic(bx - 3584, tid, Wn2, Wn2, 256, 256, 256, Wn2pk); return; }
    // gather: hidden_pk = bf16(emb[items]) in A-fragment-packed layout
    {
        int i = (bx - 3840) * 256 + tid;
        int mg = i >> 9;
        int rem = i & 511;
        int l = rem & 63;
        int m = mg * 16 + (l & 15);
        int k = (rem >> 6) * 32 + (l >> 4) * 8;
        int it = items[m];
        const float* src = emb + (size_t)it * 256 + k;
        float4 v0 = *(const float4*)src;
        float4 v1 = *(const float4*)(src + 4);
        uint4 o;
        o.x = f2bf(v0.x) | ((unsigned)f2bf(v0.y) << 16);
        o.y = f2bf(v0.z) | ((unsigned)f2bf(v0.w) << 16);
        o.z = f2bf(v1.x) | ((unsigned)f2bf(v1.y) << 16);
        o.w = f2bf(v1.z) | ((unsigned)f2bf(v1.w) << 16);
        *(uint4*)(hidden_pk + (size_t)i * 8) = o;
    }
}

// ---------------------------------------------------------------------------
// K2: FUSED hio + adjacency (R15-proven form).
// ---------------------------------------------------------------------------
__global__ __launch_bounds__(256) void gemm_hioadj(
    const unsigned short* __restrict__ hidden_pk,
    const unsigned short* __restrict__ Wio_pk,
    const float* __restrict__ bein, const float* __restrict__ beout,
    const float* __restrict__ A,
    const float* __restrict__ biah, const float* __restrict__ boah,
    unsigned short* __restrict__ inp_pk)
{
    __shared__ unsigned short SM[24576];   // 48KB
    unsigned short* As0 = SM;              // phase1 A dbuf [2][4096]
    unsigned short* Bs0 = SM + 8192;       // phase1 B dbuf [2][4096]
    unsigned short* Hb  = SM;              // phase2 hio tile (overlaps, 16384)
    unsigned short* Ab  = SM + 16384;      // phase2 adjacency frags (8192)

    const int tid = threadIdx.x;
    const int wid = tid >> 6, lane = tid & 63;
    const int wr = wid >> 1, wc = wid & 1;
    const int bm = blockIdx.x * 128;
    const int nt = blockIdx.y;
    const int mg0 = bm >> 4;
    const int b0 = blockIdx.x * 2;
    const int half = nt >> 1;

    auto stage = [&](int kt, int buf) {
        #pragma unroll
        for (int u = 0; u < 2; ++u) {
            int rg = wid * 2 + u;
            gl_lds16(hidden_pk + ((size_t)(mg0 + rg) * 8 + kt) * 512 + lane * 8,
                     &As0[buf * 4096 + rg * 512]);
            gl_lds16(Wio_pk + ((size_t)(kt * 4 + nt) * 8 + rg) * 512 + lane * 8,
                     &Bs0[buf * 4096 + rg * 512]);
        }
    };

    floatx4 acc[4][4] = {};
    stage(0, 0);
    __syncthreads();
    #pragma unroll
    for (int kt = 0; kt < 8; ++kt) {
        int cur = kt & 1;
        if (kt < 7) stage(kt + 1, cur ^ 1);
        bhalf8 a[4], b[4];
        #pragma unroll
        for (int i = 0; i < 4; i++) a[i] = *(const bhalf8*)&As0[cur * 4096 + (wr * 4 + i) * 512 + lane * 8];
        #pragma unroll
        for (int j = 0; j < 4; j++) b[j] = *(const bhalf8*)&Bs0[cur * 4096 + (wc * 4 + j) * 512 + lane * 8];
        #pragma unroll
        for (int i = 0; i < 4; i++)
            #pragma unroll
            for (int j = 0; j < 4; j++) acc[i][j] = mfma16(a[i], b[j], acc[i][j]);
        __syncthreads();
    }
    const int r0 = (lane >> 4) * 4;
    // Epilogue 1: bias + pack into LDS Hb (B-fragment layout).
    {
        const float* bio = half ? beout : bein;
        #pragma unroll
        for (int mf = 0; mf < 4; mf++) {
            #pragma unroll
            for (int nf = 0; nf < 4; nf++) {
                int nl = wc * 64 + nf * 16 + (lane & 15);
                float bias = bio[(nt & 1) * 128 + nl];
                int base = (((wr * 2 + (mf >> 1)) * 8 + (nl >> 4)) * 64
                            + ((mf & 1) * 2 + (r0 >> 3)) * 16 + (lane & 15)) * 8 + (r0 & 7);
                ushort4 o;
                o.x = f2bf(acc[mf][nf][0] + bias);
                o.y = f2bf(acc[mf][nf][1] + bias);
                o.z = f2bf(acc[mf][nf][2] + bias);
                o.w = f2bf(acc[mf][nf][3] + bias);
                *(ushort4*)&Hb[base] = o;
            }
        }
    }
    // Stage adjacency A-frags for both batches (f32->bf16).
    {
        int r = tid >> 2, jj = tid & 3;
        #pragma unroll
        for (int bb = 0; bb < 2; ++bb)
            #pragma unroll
            for (int kt2 = 0; kt2 < 2; ++kt2) {
                const float* src = A + (size_t)(b0 + bb) * 8192 + r * 128 + half * 64 + kt2 * 32 + jj * 8;
                float4 v0 = *(const float4*)src;
                float4 v1 = *(const float4*)(src + 4);
                uint4 o;
                o.x = f2bf(v0.x) | ((unsigned)f2bf(v0.y) << 16);
                o.y = f2bf(v0.z) | ((unsigned)f2bf(v0.w) << 16);
                o.z = f2bf(v1.x) | ((unsigned)f2bf(v1.y) << 16);
                o.w = f2bf(v1.z) | ((unsigned)f2bf(v1.w) << 16);
                *(uint4*)&Ab[(bb * 2 + kt2) * 2048 + ((r >> 4) * 64 + jj * 16 + (r & 15)) * 8] = o;
            }
    }
    __syncthreads();
    // Phase 2: wave handles batch bb = wid>>1, col-half ch = wid&1.
    const int bb = wid >> 1, ch = wid & 1;
    floatx4 acc2[4][4] = {};
    #pragma unroll
    for (int kt2 = 0; kt2 < 2; ++kt2) {
        bhalf8 a2[4];
        #pragma unroll
        for (int i = 0; i < 4; i++)
            a2[i] = *(const bhalf8*)&Ab[(bb * 2 + kt2) * 2048 + (i * 64 + lane) * 8];
        #pragma unroll
        for (int jf = 0; jf < 4; jf++) {
            bhalf8 bv = *(const bhalf8*)&Hb[((bb * 2 + kt2) * 8 + ch * 4 + jf) * 512 + lane * 8];
            #pragma unroll
            for (int i = 0; i < 4; i++) acc2[i][jf] = mfma16(a2[i], bv, acc2[i][jf]);
        }
    }
    // Epilogue 2: write inp_pk (A-frag packed).
    {
        const float* bia = half ? boah : biah;
        const int b = b0 + bb;
        #pragma unroll
        for (int i = 0; i < 4; i++) {
            #pragma unroll
            for (int jf = 0; jf < 4; jf++) {
                int colp = (nt & 1) * 128 + (ch * 4 + jf) * 16 + (lane & 15);
                float bv = bia[colp];
                int kt5 = nt * 4 + ch * 2 + (jf >> 1);
                int l2 = ((jf & 1) * 2 + ((lane >> 3) & 1)) * 16;
                #pragma unroll
                for (int reg = 0; reg < 4; reg++) {
                    int mlo = r0 + reg;
                    size_t dst = (((size_t)(b * 4 + i) * 16 + kt5) * 64 + l2 + mlo) * 8 + (lane & 7);
                    inp_pk[dst] = f2bf(acc2[i][jf][reg] + bv);
                }
            }
        }
    }
}

// ---------------------------------------------------------------------------
// K4: GRU cell v10: dt-PAIR blocks (512 thr, grid (256,2)) with the
// R8/R11-proven counted-vmcnt pipeline.  Per-wave work identical to R11
// (wave = 64 rows x 32 d, 24 MFMA + 10KB LDS reads per stage, acc 128 f32).
// A 3-deep (8KB/stage), B 2-deep (24KB/stage) = 72KB LDS -> 2 blocks/CU;
// grid 512 = ALL blocks co-resident (no dispatch tail).  Per-wave loads:
// 1 A + 3 B per stage; prologue A0,B0,A1 (5); steady vmcnt(1), final (0).
// NO min-waves launch bound (R7 lesson).  Epilogue untouched (R12/R13 lesson).
// ---------------------------------------------------------------------------
__global__ __launch_bounds__(512) void gru_mfma(
    const unsigned short* __restrict__ inp_pk,
    const unsigned short* __restrict__ hidden_pk,
    const unsigned short* __restrict__ Wg_pk,
    const float* __restrict__ bi, const float* __restrict__ bh,
    unsigned short* __restrict__ newh_bf)
{
    __shared__ unsigned short As3[3][4096];     // 3 x 8KB
    __shared__ unsigned short Bs2[2][12288];    // 2 x 24KB
    const int tid = threadIdx.x;
    const int wid = tid >> 6, lane = tid & 63;  // wid 0..7
    const int wr = wid >> 2, wc2 = wid & 3;     // wave = rows wr*64.. x cols wc2*32..
    const int bm = blockIdx.x * 128;
    const int dp = blockIdx.y;                  // dt-pair (128 cols)
    const int mg0 = bm >> 4;
    const int dtl = wc2 >> 1, hh = wc2 & 1;     // which dt of pair, which 32-col half

    floatx4 R[4][2] = {}, I[4][2] = {}, N0[4][2] = {}, N1[4][2] = {};

    auto stageA = [&](int st, int buf) {
        const unsigned short* src = (st < 16)
            ? inp_pk    + ((size_t)(mg0 + wid) * 16 + st) * 512
            : hidden_pk + ((size_t)(mg0 + wid) * 8 + (st - 16)) * 512;
        gl_lds16(src + lane * 8, &As3[buf][wid * 512]);
    };
    auto stageB = [&](int st, int buf) {
        #pragma unroll
        for (int u = 0; u < 3; ++u) {
            int sg = wid * 3 + u;            // 0..23 = dl*12 + g*4 + q
            int dl = sg / 12;
            int rem = sg - dl * 12;
            gl_lds16(Wg_pk + ((size_t)(st * 4 + dp * 2 + dl) * 12 + rem) * 512 + lane * 8,
                     &Bs2[buf][sg * 512]);
        }
    };

    // prologue issue order defines vmcnt counting: A0(1), B0(3), A1(1)
    stageA(0, 0);
    stageB(0, 0);
    stageA(1, 1);
    #pragma unroll
    for (int st = 0; st < 24; ++st) {
        const int ca = st % 3, cb = st & 1;
        if (st < 23) asm volatile("s_waitcnt vmcnt(1)" ::: "memory");
        else         asm volatile("s_waitcnt vmcnt(0)" ::: "memory");
        __builtin_amdgcn_s_barrier();
        __builtin_amdgcn_sched_barrier(0);
        if (st < 23) stageB(st + 1, cb ^ 1);
        if (st < 22) stageA(st + 2, (st + 2) % 3);
        bhalf8 a[4];
        #pragma unroll
        for (int i = 0; i < 4; i++)
            a[i] = *(const bhalf8*)&As3[ca][(wr * 4 + i) * 512 + lane * 8];
        #pragma unroll
        for (int f = 0; f < 2; ++f) {
            bhalf8 bv = *(const bhalf8*)&Bs2[cb][(dtl * 12 + 0 * 4 + hh * 2 + f) * 512 + lane * 8];
            #pragma unroll
            for (int i = 0; i < 4; i++) R[i][f] = mfma16(a[i], bv, R[i][f]);
        }
        #pragma unroll
        for (int f = 0; f < 2; ++f) {
            bhalf8 bv = *(const bhalf8*)&Bs2[cb][(dtl * 12 + 1 * 4 + hh * 2 + f) * 512 + lane * 8];
            #pragma unroll
            for (int i = 0; i < 4; i++) I[i][f] = mfma16(a[i], bv, I[i][f]);
        }
        if (st < 16) {
            #pragma unroll
            for (int f = 0; f < 2; ++f) {
                bhalf8 bv = *(const bhalf8*)&Bs2[cb][(dtl * 12 + 2 * 4 + hh * 2 + f) * 512 + lane * 8];
                #pragma unroll
                for (int i = 0; i < 4; i++) N0[i][f] = mfma16(a[i], bv, N0[i][f]);
            }
        } else {
            #pragma unroll
            for (int f = 0; f < 2; ++f) {
                bhalf8 bv = *(const bhalf8*)&Bs2[cb][(dtl * 12 + 2 * 4 + hh * 2 + f) * 512 + lane * 8];
                #pragma unroll
                for (int i = 0; i < 4; i++) N1[i][f] = mfma16(a[i], bv, N1[i][f]);
            }
        }
    }
    // Gates epilogue: wave owns rows [bm+wr*64, +64), d [dp*128+wc2*32, +32)
    const int r0 = (lane >> 4) * 4;
    const int bd = dp * 128 + wc2 * 32;
    #pragma unroll
    for (int i = 0; i < 4; i++) {
        #pragma unroll
        for (int f = 0; f < 2; f++) {
            int d = bd + f * 16 + (lane & 15);
            float bir = bi[d] + bh[d];
            float bii = bi[256 + d] + bh[256 + d];
            float bin = bi[512 + d];
            float bhn = bh[512 + d];
            #pragma unroll
            for (int reg = 0; reg < 4; reg++) {
                int m = bm + wr * 64 + i * 16 + r0 + reg;
                size_t hidx = (((size_t)(m >> 4) * 8 + (d >> 5)) * 64
                               + ((d >> 3) & 3) * 16 + (m & 15)) * 8 + (d & 7);
                float hv = bf2f(hidden_pk[hidx]);
                float rg = sigmoidf_(R[i][f][reg] + bir);
                float ig = sigmoidf_(I[i][f][reg] + bii);
                float ng = tanhf(N0[i][f][reg] + bin + rg * (N1[i][f][reg] + bhn));
                newh_bf[(size_t)m * 256 + d] = f2bf(ng + ig * (hv - ng));
            }
        }
    }
}

// ---------------------------------------------------------------------------
// K5: fused attention; ht computed in-block; 2-phase dbuf kt-loop
// (R16-proven form).
// ---------------------------------------------------------------------------
__global__ __launch_bounds__(256) void attn_fused(
    const unsigned short* __restrict__ newh_bf,
    const int* __restrict__ alias, const int* __restrict__ mask,
    const float* __restrict__ W1, const float* __restrict__ b1,
    const float* __restrict__ b2, const float* __restrict__ W3,
    const unsigned short* __restrict__ W2pk,
    unsigned short* __restrict__ ht_bf,
    unsigned short* __restrict__ a_bf)
{
    const int b = blockIdx.x;
    const int tid = threadIdx.x;
    const int wid = tid >> 6, lane = tid & 63;
    __shared__ int arow[64];
    __shared__ int node_s;
    __shared__ float hts[256];
    __shared__ float q1s[256];
    __shared__ float alphap[4][64];
    __shared__ float am[64];
    __shared__ unsigned short As[2][2048];
    __shared__ unsigned short Bs[2][8192];
    if (tid < 64) {
        arow[tid] = b * 64 + alias[b * 64 + tid];
        int mv = mask[b * 64 + tid];
        #pragma unroll
        for (int off = 32; off > 0; off >>= 1) mv += __shfl_xor(mv, off);
        if (tid == 0) node_s = b * 64 + alias[b * 64 + (mv - 1)];
    }
    __syncthreads();
    {
        unsigned short hv = newh_bf[(size_t)node_s * 256 + tid];
        ht_bf[(size_t)b * 256 + tid] = hv;
        hts[tid] = bf2f(hv);
    }
    __syncthreads();

    auto stage = [&](int kt, int buf) {
        {
            int r = tid >> 2, jj = tid & 3;
            const unsigned short* src = newh_bf + (size_t)arow[r] * 256 + kt * 32 + jj * 8;
            *(uint4*)&As[buf][((r >> 4) * 64 + jj * 16 + (r & 15)) * 8] = *(const uint4*)src;
        }
        {
            const unsigned short* src = W2pk + (size_t)kt * 16 * 512;
            #pragma unroll
            for (int u = 0; u < 4; ++u) {
                int sg = wid * 4 + u;
                gl_lds16(src + sg * 512 + lane * 8, &Bs[buf][sg * 512]);
            }
        }
    };

    floatx4 acc[4][4] = {};
    stage(0, 0);
    {   // q1[d] = sum_k ht[k]*W1[k][d] + b1[d]   (f32) — overlaps stage(0) latency
        float q0 = 0, q1v = 0, q2v = 0, q3v = 0;
        for (int k = 0; k < 256; k += 4) {
            q0  = fmaf(hts[k],     W1[(size_t)k * 256 + tid],       q0);
            q1v = fmaf(hts[k + 1], W1[(size_t)(k + 1) * 256 + tid], q1v);
            q2v = fmaf(hts[k + 2], W1[(size_t)(k + 2) * 256 + tid], q2v);
            q3v = fmaf(hts[k + 3], W1[(size_t)(k + 3) * 256 + tid], q3v);
        }
        q1s[tid] = (q0 + q1v) + (q2v + q3v) + b1[tid];
    }
    __syncthreads();
    #pragma unroll
    for (int kt = 0; kt < 8; ++kt) {
        int cur = kt & 1;
        if (kt < 7) stage(kt + 1, cur ^ 1);
        bhalf8 a[4], bb[4];
        #pragma unroll
        for (int i = 0; i < 4; i++) a[i] = *(const bhalf8*)&As[cur][(i * 64 + lane) * 8];
        #pragma unroll
        for (int j = 0; j < 4; j++) bb[j] = *(const bhalf8*)&Bs[cur][((wid * 4 + j) * 64 + lane) * 8];
        #pragma unroll
        for (int i = 0; i < 4; i++)
            #pragma unroll
            for (int j = 0; j < 4; j++) acc[i][j] = mfma16(a[i], bb[j], acc[i][j]);
        __syncthreads();
    }
    float q1v[4], b2v[4], w3v[4];
    #pragma unroll
    for (int j = 0; j < 4; j++) {
        int col = wid * 64 + j * 16 + (lane & 15);
        q1v[j] = q1s[col];
        b2v[j] = b2[col];
        w3v[j] = W3[col];
    }
    #pragma unroll
    for (int i = 0; i < 4; i++) {
        #pragma unroll
        for (int reg = 0; reg < 4; reg++) {
            float t = 0.f;
            #pragma unroll
            for (int j = 0; j < 4; j++)
                t += sigmoidf_(acc[i][j][reg] + q1v[j] + b2v[j]) * w3v[j];
            #pragma unroll
            for (int off = 1; off < 16; off <<= 1) t += __shfl_xor(t, off);
            if ((lane & 15) == 0) alphap[wid][i * 16 + (lane >> 4) * 4 + reg] = t;
        }
    }
    __syncthreads();
    if (tid < 64) {
        float al = alphap[0][tid] + alphap[1][tid] + alphap[2][tid] + alphap[3][tid];
        am[tid] = al * (float)mask[b * 64 + tid];
    }
    __syncthreads();
    float acca = 0.f;
    #pragma unroll 8
    for (int l = 0; l < 64; ++l)
        acca = fmaf(am[l], bf2f(newh_bf[(size_t)arow[l] * 256 + tid]), acca);
    a_bf[(size_t)b * 256 + tid] = f2bf(acca);
}

// ---------------------------------------------------------------------------
// K6: fused final MLP, BK=64 (R14-proven form).
// BM=64, 8 blocks; y kept in LDS in A-fragment layout.
// ---------------------------------------------------------------------------
__global__ __launch_bounds__(256) void mlp_fused(
    const unsigned short* __restrict__ a_bf, const unsigned short* __restrict__ ht_bf,
    const unsigned short* __restrict__ Wn1pk, const float* __restrict__ bn1,
    const unsigned short* __restrict__ Wn2pk, const float* __restrict__ bn2,
    float* __restrict__ out)
{
    __shared__ unsigned short As[4096];     // 2 kt x 4 m-frags
    __shared__ unsigned short Bs[16384];    // 2 kt x 16 n-frags
    __shared__ unsigned short Ys[16384];    // y (64 x 256) A-frag layout
    const int tid = threadIdx.x;
    const int wid = tid >> 6, lane = tid & 63;
    const int bm = blockIdx.x * 64;
    const int c = lane & 15;
    const int r0 = (lane >> 4) * 4;

    {
        floatx4 acc[4][4] = {};
        #pragma unroll
        for (int s = 0; s < 8; ++s) {
            #pragma unroll
            for (int v = 0; v < 2; ++v) {
                int kt = s * 2 + v;
                int r = tid >> 2, jj = tid & 3;
                const unsigned short* src = ((kt < 8) ? a_bf : ht_bf)
                    + (size_t)(bm + r) * 256 + (kt & 7) * 32 + jj * 8;
                *(uint4*)&As[v * 2048 + ((r >> 4) * 64 + jj * 16 + (r & 15)) * 8] = *(const uint4*)src;
            }
            #pragma unroll
            for (int u = 0; u < 8; ++u) {
                int sg = wid * 8 + u;
                int ktl = sg >> 4, f = sg & 15;
                gl_lds16(Wn1pk + ((size_t)(s * 2 + ktl) * 16 + f) * 512 + lane * 8, &Bs[sg * 512]);
            }
            __syncthreads();
            #pragma unroll
            for (int v = 0; v < 2; ++v) {
                bhalf8 a[4], bb[4];
                #pragma unroll
                for (int i = 0; i < 4; i++) a[i] = *(const bhalf8*)&As[v * 2048 + (i * 64 + lane) * 8];
                #pragma unroll
                for (int j = 0; j < 4; j++) bb[j] = *(const bhalf8*)&Bs[((v * 16) + wid * 4 + j) * 512 + lane * 8];
                #pragma unroll
                for (int i = 0; i < 4; i++)
                    #pragma unroll
                    for (int j = 0; j < 4; j++) acc[i][j] = mfma16(a[i], bb[j], acc[i][j]);
            }
            __syncthreads();
        }
        #pragma unroll
        for (int i = 0; i < 4; i++) {
            #pragma unroll
            for (int jf = 0; jf < 4; jf++) {
                int n = wid * 64 + jf * 16 + c;
                float bv = bn1[n];
                int kt2 = wid * 2 + (jf >> 1);
                int l2 = ((jf & 1) * 2 + (c >> 3)) * 16;
                #pragma unroll
                for (int reg = 0; reg < 4; reg++) {
                    float v = fmaxf(acc[i][jf][reg] + bv, 0.f);
                    size_t idx = (((size_t)(kt2 * 4 + i) * 64) + l2 + r0 + reg) * 8 + (c & 7);
                    Ys[idx] = f2bf(v);
                }
            }
        }
    }
    __syncthreads();
    floatx4 acc2[4][4] = {};
    #pragma unroll
    for (int s = 0; s < 4; ++s) {
        #pragma unroll
        for (int u = 0; u < 8; ++u) {
            int sg = wid * 8 + u;
            int ktl = sg >> 4, f = sg & 15;
            gl_lds16(Wn2pk + ((size_t)(s * 2 + ktl) * 16 + f) * 512 + lane * 8, &Bs[sg * 512]);
        }
        __syncthreads();
        #pragma unroll
        for (int v = 0; v < 2; ++v) {
            int kt2 = s * 2 + v;
            bhalf8 a[4], bb[4];
            #pragma unroll
            for (int i = 0; i < 4; i++) a[i] = *(const bhalf8*)&Ys[((kt2 * 4 + i) * 64 + lane) * 8];
            #pragma unroll
            for (int j = 0; j < 4; j++) bb[j] = *(const bhalf8*)&Bs[((v * 16) + wid * 4 + j) * 512 + lane * 8];
            #pragma unroll
            for (int i = 0; i < 4; i++)
                #pragma unroll
                for (int j = 0; j < 4; j++) acc2[i][j] = mfma16(a[i], bb[j], acc2[i][j]);
        }
        __syncthreads();
    }
    #pragma unroll
    for (int i = 0; i < 4; i++) {
        #pragma unroll
        for (int jf = 0; jf < 4; jf++) {
            int n = wid * 64 + jf * 16 + c;
            float bv = bn2[n];
            #pragma unroll
            for (int reg = 0; reg < 4; reg++) {
                int m = bm + i * 16 + r0 + reg;
                out[(size_t)m * 256 + n] = acc2[i][jf][reg] + bv;
            }
        }
    }
}

// ---------------------------------------------------------------------------
extern "C" void kernel_launch(void* const* d_in, const int* in_sizes, int n_in,
                              void* d_out, int out_size, void* d_ws, size_t ws_size,
                              hipStream_t stream)
{
    const int*   alias  = (const int*)  d_in[0];
    const float* A      = (const float*)d_in[1];
    const int*   items  = (const int*)  d_in[2];
    const int*   mask   = (const int*)  d_in[3];
    const float* emb    = (const float*)d_in[4];
    const float* W_ein  = (const float*)d_in[5];
    const float* b_ein  = (const float*)d_in[6];
    const float* W_eout = (const float*)d_in[7];
    const float* b_eout = (const float*)d_in[8];
    const float* b_iah  = (const float*)d_in[9];
    const float* b_oah  = (const float*)d_in[10];
    const float* W_i    = (const float*)d_in[11];
    const float* b_i    = (const float*)d_in[12];
    const float* W_h    = (const float*)d_in[13];
    const float* b_h    = (const float*)d_in[14];
    const float* W1     = (const float*)d_in[15];
    const float* b1     = (const float*)d_in[16];
    const float* W2     = (const float*)d_in[17];
    const float* b2     = (const float*)d_in[18];
    const float* W3     = (const float*)d_in[19];
    const float* Wn1    = (const float*)d_in[20];
    const float* bn1    = (const float*)d_in[21];
    const float* Wn2    = (const float*)d_in[22];
    const float* bn2    = (const float*)d_in[23];
    float* out = (float*)d_out;
    (void)in_sizes; (void)n_in; (void)out_size; (void)ws_size;

    char* w = (char*)d_ws;
    unsigned short* hidden_pk = (unsigned short*)(w);                 // 16,777,216
    unsigned short* inp_pk    = (unsigned short*)(w + 50331648);      // 33,554,432
    unsigned short* newh_bf   = (unsigned short*)(w + 83886080);      // 16,777,216
    unsigned short* Wio_pk    = (unsigned short*)(w + 100663296);     //    262,144
    unsigned short* Wg_pk     = (unsigned short*)(w + 100925440);     //  1,179,648
    unsigned short* W2pk      = (unsigned short*)(w + 102105088);     //    131,072
    unsigned short* Wn1pk     = (unsigned short*)(w + 102236160);     //    262,144
    unsigned short* Wn2pk     = (unsigned short*)(w + 102498304);     //    131,072
    unsigned short* ht_bf     = (unsigned short*)(w + 102629376);     //    262,144
    unsigned short* a_bf      = (unsigned short*)(w + 102891520);     //    262,144

    pack_all   <<<7936, 256, 0, stream>>>(W_ein, W_eout, W_i, W_h, W2, Wn1, Wn2,
                                          items, emb,
                                          Wio_pk, Wg_pk, W2pk, Wn1pk, Wn2pk, hidden_pk);
    gemm_hioadj<<<dim3(256, 4), 256, 0, stream>>>(hidden_pk, Wio_pk, b_ein, b_eout,
                                                  A, b_iah, b_oah, inp_pk);
    gru_mfma   <<<dim3(256, 2), 512, 0, stream>>>(inp_pk, hidden_pk, Wg_pk, b_i, b_h, newh_bf);
    attn_fused <<<512, 256, 0, stream>>>(newh_bf, alias, mask, W1, b1, b2, W3, W2pk, ht_bf, a_bf);
    mlp_fused  <<<8, 256, 0, stream>>>(a_bf, ht_bf, Wn1pk, bn1, Wn2pk, bn2, out);
}

// Round 18
// 137.015 us; speedup vs baseline: 1.0448x; 1.0448x over previous
//
#include <hip/hip_runtime.h>
#include <hip/hip_bf16.h>
#include <math.h>

typedef short bhalf8 __attribute__((ext_vector_type(8)));
typedef float floatx4 __attribute__((ext_vector_type(4)));

__device__ __forceinline__ float sigmoidf_(float x) { return 1.0f / (1.0f + __expf(-x)); }

__device__ __forceinline__ unsigned short f2bf(float f) {
    unsigned int u = __builtin_bit_cast(unsigned int, f);
    u += 0x7FFFu + ((u >> 16) & 1u);
    return (unsigned short)(u >> 16);
}
__device__ __forceinline__ float bf2f(unsigned short h) {
    unsigned int u = ((unsigned int)h) << 16;
    return __builtin_bit_cast(float, u);
}

__device__ __forceinline__ floatx4 mfma16(bhalf8 a, bhalf8 b, floatx4 c) {
    return __builtin_amdgcn_mfma_f32_16x16x32_bf16(a, b, c, 0, 0, 0);
}

// async global->LDS, 16B/lane: LDS dest = wave-uniform base + lane*16.
__device__ __forceinline__ void gl_lds16(const unsigned short* g, unsigned short* l) {
    __builtin_amdgcn_global_load_lds(
        (const __attribute__((address_space(1))) void*)g,
        (__attribute__((address_space(3))) void*)l, 16, 0, 0);
}

// ---------------------------------------------------------------------------
// pack helpers: f32 [K][N] -> bf16 B-fragment-linear tiles.
// ---------------------------------------------------------------------------
__device__ __forceinline__ void pack_generic(
    int b, int tid, const float* __restrict__ W0, const float* __restrict__ W1,
    int split, int N, int BN, unsigned short* __restrict__ out)
{
    int t = b * 256 + tid;
    int j = t & 7;
    int lane = (t >> 3) & 63;
    int FT = BN >> 4;
    int f = (t >> 9) % FT;
    int rest = t / (512 * FT);
    int NT = N / BN;
    int nt = rest % NT;
    int kt = rest / NT;
    int k = kt * 32 + (lane >> 4) * 8 + j;
    int n = nt * BN + f * 16 + (lane & 15);
    float v = (n < split) ? W0[(size_t)k * split + n]
                          : W1[(size_t)k * (N - split) + (n - split)];
    out[t] = f2bf(v);
}

// combined GRU pack: Wcat[768][768] = [W_i ; W_h]
__device__ __forceinline__ void pack_gru_(
    int b, int tid, const float* __restrict__ Wi, const float* __restrict__ Wh,
    unsigned short* __restrict__ out)
{
    int t = b * 256 + tid;
    int j = t & 7;
    int lane = (t >> 3) & 63;
    int f = (t >> 9) & 3;
    int q = t >> 11;
    int g = q % 3;
    int p = q / 3;
    int dt = p & 3;
    int kt = p >> 2;
    int k = kt * 32 + (lane >> 4) * 8 + j;
    int n = g * 256 + dt * 64 + f * 16 + (lane & 15);
    float v = (k < 512) ? Wi[(size_t)k * 768 + n] : Wh[(size_t)(k - 512) * 768 + n];
    out[t] = f2bf(v);
}

// P0: all weight packs + embedding gather in ONE launch (7936 blocks)
__global__ __launch_bounds__(256) void pack_all(
    const float* __restrict__ W_ein, const float* __restrict__ W_eout,
    const float* __restrict__ Wi, const float* __restrict__ Wh,
    const float* __restrict__ W2, const float* __restrict__ Wn1,
    const float* __restrict__ Wn2,
    const int* __restrict__ items, const float* __restrict__ emb,
    unsigned short* __restrict__ Wio_pk, unsigned short* __restrict__ Wg_pk,
    unsigned short* __restrict__ W2pk, unsigned short* __restrict__ Wn1pk,
    unsigned short* __restrict__ Wn2pk, unsigned short* __restrict__ hidden_pk)
{
    int bx = blockIdx.x;
    int tid = threadIdx.x;
    if (bx < 512)       { pack_generic(bx,        tid, W_ein, W_eout, 256, 512, 128, Wio_pk); return; }
    if (bx < 2816)      { pack_gru_   (bx - 512,  tid, Wi, Wh, Wg_pk); return; }
    if (bx < 3072)      { pack_generic(bx - 2816, tid, W2,  W2,  256, 256, 256, W2pk); return; }
    if (bx < 3584)      { pack_generic(bx - 3072, tid, Wn1, Wn1, 256, 256, 256, Wn1pk); return; }
    if (bx < 3840)      { pack_generic(bx - 3584, tid, Wn2, Wn2, 256, 256, 256, Wn2pk); return; }
    // gather: hidden_pk = bf16(emb[items]) in A-fragment-packed layout
    {
        int i = (bx - 3840) * 256 + tid;
        int mg = i >> 9;
        int rem = i & 511;
        int l = rem & 63;
        int m = mg * 16 + (l & 15);
        int k = (rem >> 6) * 32 + (l >> 4) * 8;
        int it = items[m];
        const float* src = emb + (size_t)it * 256 + k;
        float4 v0 = *(const float4*)src;
        float4 v1 = *(const float4*)(src + 4);
        uint4 o;
        o.x = f2bf(v0.x) | ((unsigned)f2bf(v0.y) << 16);
        o.y = f2bf(v0.z) | ((unsigned)f2bf(v0.w) << 16);
        o.z = f2bf(v1.x) | ((unsigned)f2bf(v1.y) << 16);
        o.w = f2bf(v1.z) | ((unsigned)f2bf(v1.w) << 16);
        *(uint4*)(hidden_pk + (size_t)i * 8) = o;
    }
}

// ---------------------------------------------------------------------------
// K2: FUSED hio + adjacency (R15-proven form).
// ---------------------------------------------------------------------------
__global__ __launch_bounds__(256) void gemm_hioadj(
    const unsigned short* __restrict__ hidden_pk,
    const unsigned short* __restrict__ Wio_pk,
    const float* __restrict__ bein, const float* __restrict__ beout,
    const float* __restrict__ A,
    const float* __restrict__ biah, const float* __restrict__ boah,
    unsigned short* __restrict__ inp_pk)
{
    __shared__ unsigned short SM[24576];   // 48KB
    unsigned short* As0 = SM;              // phase1 A dbuf [2][4096]
    unsigned short* Bs0 = SM + 8192;       // phase1 B dbuf [2][4096]
    unsigned short* Hb  = SM;              // phase2 hio tile (overlaps, 16384)
    unsigned short* Ab  = SM + 16384;      // phase2 adjacency frags (8192)

    const int tid = threadIdx.x;
    const int wid = tid >> 6, lane = tid & 63;
    const int wr = wid >> 1, wc = wid & 1;
    const int bm = blockIdx.x * 128;
    const int nt = blockIdx.y;
    const int mg0 = bm >> 4;
    const int b0 = blockIdx.x * 2;
    const int half = nt >> 1;

    auto stage = [&](int kt, int buf) {
        #pragma unroll
        for (int u = 0; u < 2; ++u) {
            int rg = wid * 2 + u;
            gl_lds16(hidden_pk + ((size_t)(mg0 + rg) * 8 + kt) * 512 + lane * 8,
                     &As0[buf * 4096 + rg * 512]);
            gl_lds16(Wio_pk + ((size_t)(kt * 4 + nt) * 8 + rg) * 512 + lane * 8,
                     &Bs0[buf * 4096 + rg * 512]);
        }
    };

    floatx4 acc[4][4] = {};
    stage(0, 0);
    __syncthreads();
    #pragma unroll
    for (int kt = 0; kt < 8; ++kt) {
        int cur = kt & 1;
        if (kt < 7) stage(kt + 1, cur ^ 1);
        bhalf8 a[4], b[4];
        #pragma unroll
        for (int i = 0; i < 4; i++) a[i] = *(const bhalf8*)&As0[cur * 4096 + (wr * 4 + i) * 512 + lane * 8];
        #pragma unroll
        for (int j = 0; j < 4; j++) b[j] = *(const bhalf8*)&Bs0[cur * 4096 + (wc * 4 + j) * 512 + lane * 8];
        #pragma unroll
        for (int i = 0; i < 4; i++)
            #pragma unroll
            for (int j = 0; j < 4; j++) acc[i][j] = mfma16(a[i], b[j], acc[i][j]);
        __syncthreads();
    }
    const int r0 = (lane >> 4) * 4;
    // Epilogue 1: bias + pack into LDS Hb (B-fragment layout).
    {
        const float* bio = half ? beout : bein;
        #pragma unroll
        for (int mf = 0; mf < 4; mf++) {
            #pragma unroll
            for (int nf = 0; nf < 4; nf++) {
                int nl = wc * 64 + nf * 16 + (lane & 15);
                float bias = bio[(nt & 1) * 128 + nl];
                int base = (((wr * 2 + (mf >> 1)) * 8 + (nl >> 4)) * 64
                            + ((mf & 1) * 2 + (r0 >> 3)) * 16 + (lane & 15)) * 8 + (r0 & 7);
                ushort4 o;
                o.x = f2bf(acc[mf][nf][0] + bias);
                o.y = f2bf(acc[mf][nf][1] + bias);
                o.z = f2bf(acc[mf][nf][2] + bias);
                o.w = f2bf(acc[mf][nf][3] + bias);
                *(ushort4*)&Hb[base] = o;
            }
        }
    }
    // Stage adjacency A-frags for both batches (f32->bf16).
    {
        int r = tid >> 2, jj = tid & 3;
        #pragma unroll
        for (int bb = 0; bb < 2; ++bb)
            #pragma unroll
            for (int kt2 = 0; kt2 < 2; ++kt2) {
                const float* src = A + (size_t)(b0 + bb) * 8192 + r * 128 + half * 64 + kt2 * 32 + jj * 8;
                float4 v0 = *(const float4*)src;
                float4 v1 = *(const float4*)(src + 4);
                uint4 o;
                o.x = f2bf(v0.x) | ((unsigned)f2bf(v0.y) << 16);
                o.y = f2bf(v0.z) | ((unsigned)f2bf(v0.w) << 16);
                o.z = f2bf(v1.x) | ((unsigned)f2bf(v1.y) << 16);
                o.w = f2bf(v1.z) | ((unsigned)f2bf(v1.w) << 16);
                *(uint4*)&Ab[(bb * 2 + kt2) * 2048 + ((r >> 4) * 64 + jj * 16 + (r & 15)) * 8] = o;
            }
    }
    __syncthreads();
    // Phase 2: wave handles batch bb = wid>>1, col-half ch = wid&1.
    const int bb = wid >> 1, ch = wid & 1;
    floatx4 acc2[4][4] = {};
    #pragma unroll
    for (int kt2 = 0; kt2 < 2; ++kt2) {
        bhalf8 a2[4];
        #pragma unroll
        for (int i = 0; i < 4; i++)
            a2[i] = *(const bhalf8*)&Ab[(bb * 2 + kt2) * 2048 + (i * 64 + lane) * 8];
        #pragma unroll
        for (int jf = 0; jf < 4; jf++) {
            bhalf8 bv = *(const bhalf8*)&Hb[((bb * 2 + kt2) * 8 + ch * 4 + jf) * 512 + lane * 8];
            #pragma unroll
            for (int i = 0; i < 4; i++) acc2[i][jf] = mfma16(a2[i], bv, acc2[i][jf]);
        }
    }
    // Epilogue 2: write inp_pk (A-frag packed).
    {
        const float* bia = half ? boah : biah;
        const int b = b0 + bb;
        #pragma unroll
        for (int i = 0; i < 4; i++) {
            #pragma unroll
            for (int jf = 0; jf < 4; jf++) {
                int colp = (nt & 1) * 128 + (ch * 4 + jf) * 16 + (lane & 15);
                float bv = bia[colp];
                int kt5 = nt * 4 + ch * 2 + (jf >> 1);
                int l2 = ((jf & 1) * 2 + ((lane >> 3) & 1)) * 16;
                #pragma unroll
                for (int reg = 0; reg < 4; reg++) {
                    int mlo = r0 + reg;
                    size_t dst = (((size_t)(b * 4 + i) * 16 + kt5) * 64 + l2 + mlo) * 8 + (lane & 7);
                    inp_pk[dst] = f2bf(acc2[i][jf][reg] + bv);
                }
            }
        }
    }
}

// ---------------------------------------------------------------------------
// K4: GRU cell v9 (R11/R14-proven, byte-exact): counted-vmcnt pipeline
// (A 3-deep / B 2-deep), fully unrolled, wave = 64 rows x 32 d,
// grid (256,4) x 256 thr.  R17 showed dt-pair restructure regresses
// (L2 already absorbs the A re-read).  Epilogue untouched (R12/R13 cliffs).
// ---------------------------------------------------------------------------
__global__ __launch_bounds__(256) void gru_mfma(
    const unsigned short* __restrict__ inp_pk,
    const unsigned short* __restrict__ hidden_pk,
    const unsigned short* __restrict__ Wg_pk,
    const float* __restrict__ bi, const float* __restrict__ bh,
    unsigned short* __restrict__ newh_bf)
{
    __shared__ unsigned short As3[3][4096];    // 24KB
    __shared__ unsigned short Bs2[2][6144];    // 12KB
    const int tid = threadIdx.x;
    const int wid = tid >> 6, lane = tid & 63;
    const int wr = wid >> 1, wc = wid & 1;
    const int bm = blockIdx.x * 128;
    const int dt = blockIdx.y;
    const int mg0 = bm >> 4;

    floatx4 R[4][2] = {}, I[4][2] = {}, N0[4][2] = {}, N1[4][2] = {};

    auto stageA = [&](int st, int buf) {
        #pragma unroll
        for (int u = 0; u < 2; ++u) {
            int rg = wid * 2 + u;
            const unsigned short* src = (st < 16)
                ? inp_pk    + ((size_t)(mg0 + rg) * 16 + st) * 512
                : hidden_pk + ((size_t)(mg0 + rg) * 8 + (st - 16)) * 512;
            gl_lds16(src + lane * 8, &As3[buf][rg * 512]);
        }
    };
    auto stageB = [&](int st, int buf) {
        #pragma unroll
        for (int u = 0; u < 3; ++u) {
            int sg = wid * 3 + u;
            gl_lds16(Wg_pk + ((size_t)(st * 4 + dt) * 12 + sg) * 512 + lane * 8,
                     &Bs2[buf][sg * 512]);
        }
    };

    // prologue issue order matters for vmcnt counting: A0, B0, A1
    stageA(0, 0);
    stageB(0, 0);
    stageA(1, 1);
    #pragma unroll
    for (int st = 0; st < 24; ++st) {
        const int ca = st % 3, cb = st & 1;
        if (st < 23) asm volatile("s_waitcnt vmcnt(2)" ::: "memory");
        else         asm volatile("s_waitcnt vmcnt(0)" ::: "memory");
        __builtin_amdgcn_s_barrier();
        __builtin_amdgcn_sched_barrier(0);
        if (st < 23) stageB(st + 1, cb ^ 1);
        if (st < 22) stageA(st + 2, (st + 2) % 3);
        bhalf8 a[4];
        #pragma unroll
        for (int i = 0; i < 4; i++)
            a[i] = *(const bhalf8*)&As3[ca][(wr * 4 + i) * 512 + lane * 8];
        #pragma unroll
        for (int f = 0; f < 2; ++f) {
            bhalf8 bv = *(const bhalf8*)&Bs2[cb][(0 * 4 + wc * 2 + f) * 512 + lane * 8];
            #pragma unroll
            for (int i = 0; i < 4; i++) R[i][f] = mfma16(a[i], bv, R[i][f]);
        }
        #pragma unroll
        for (int f = 0; f < 2; ++f) {
            bhalf8 bv = *(const bhalf8*)&Bs2[cb][(1 * 4 + wc * 2 + f) * 512 + lane * 8];
            #pragma unroll
            for (int i = 0; i < 4; i++) I[i][f] = mfma16(a[i], bv, I[i][f]);
        }
        if (st < 16) {
            #pragma unroll
            for (int f = 0; f < 2; ++f) {
                bhalf8 bv = *(const bhalf8*)&Bs2[cb][(2 * 4 + wc * 2 + f) * 512 + lane * 8];
                #pragma unroll
                for (int i = 0; i < 4; i++) N0[i][f] = mfma16(a[i], bv, N0[i][f]);
            }
        } else {
            #pragma unroll
            for (int f = 0; f < 2; ++f) {
                bhalf8 bv = *(const bhalf8*)&Bs2[cb][(2 * 4 + wc * 2 + f) * 512 + lane * 8];
                #pragma unroll
                for (int i = 0; i < 4; i++) N1[i][f] = mfma16(a[i], bv, N1[i][f]);
            }
        }
    }
    // Gates epilogue: wave owns rows [bm+wr*64, +64), d [dt*64+wc*32, +32)
    const int r0 = (lane >> 4) * 4;
    const int bd = dt * 64 + wc * 32;
    #pragma unroll
    for (int i = 0; i < 4; i++) {
        #pragma unroll
        for (int f = 0; f < 2; f++) {
            int d = bd + f * 16 + (lane & 15);
            float bir = bi[d] + bh[d];
            float bii = bi[256 + d] + bh[256 + d];
            float bin = bi[512 + d];
            float bhn = bh[512 + d];
            #pragma unroll
            for (int reg = 0; reg < 4; reg++) {
                int m = bm + wr * 64 + i * 16 + r0 + reg;
                size_t hidx = (((size_t)(m >> 4) * 8 + (d >> 5)) * 64
                               + ((d >> 3) & 3) * 16 + (m & 15)) * 8 + (d & 7);
                float hv = bf2f(hidden_pk[hidx]);
                float rg = sigmoidf_(R[i][f][reg] + bir);
                float ig = sigmoidf_(I[i][f][reg] + bii);
                float ng = tanhf(N0[i][f][reg] + bin + rg * (N1[i][f][reg] + bhn));
                newh_bf[(size_t)m * 256 + d] = f2bf(ng + ig * (hv - ng));
            }
        }
    }
}

// ---------------------------------------------------------------------------
// K5: fused attention; ht computed in-block; 2-phase dbuf kt-loop; the
// staged seq rows are ALSO kept in a row-major LDS copy Seq[64][264]
// (pad +8 -> 2-way-free reads), so the final a-accumulation reads LDS
// instead of 64 scattered global loads per thread.  LDS ~76KB -> 2
// blocks/CU, exactly what the 512-block grid needs.
// ---------------------------------------------------------------------------
__global__ __launch_bounds__(256) void attn_fused(
    const unsigned short* __restrict__ newh_bf,
    const int* __restrict__ alias, const int* __restrict__ mask,
    const float* __restrict__ W1, const float* __restrict__ b1,
    const float* __restrict__ b2, const float* __restrict__ W3,
    const unsigned short* __restrict__ W2pk,
    unsigned short* __restrict__ ht_bf,
    unsigned short* __restrict__ a_bf)
{
    const int b = blockIdx.x;
    const int tid = threadIdx.x;
    const int wid = tid >> 6, lane = tid & 63;
    __shared__ int arow[64];
    __shared__ int node_s;
    __shared__ float hts[256];
    __shared__ float q1s[256];
    __shared__ float alphap[4][64];
    __shared__ float am[64];
    __shared__ unsigned short As[2][2048];
    __shared__ unsigned short Bs[2][8192];
    __shared__ unsigned short Seq[64 * 264];   // row-major, pad 8
    if (tid < 64) {
        arow[tid] = b * 64 + alias[b * 64 + tid];
        int mv = mask[b * 64 + tid];
        #pragma unroll
        for (int off = 32; off > 0; off >>= 1) mv += __shfl_xor(mv, off);
        if (tid == 0) node_s = b * 64 + alias[b * 64 + (mv - 1)];
    }
    __syncthreads();
    {
        unsigned short hv = newh_bf[(size_t)node_s * 256 + tid];
        ht_bf[(size_t)b * 256 + tid] = hv;
        hts[tid] = bf2f(hv);
    }
    __syncthreads();

    auto stage = [&](int kt, int buf) {
        {
            int r = tid >> 2, jj = tid & 3;
            const unsigned short* src = newh_bf + (size_t)arow[r] * 256 + kt * 32 + jj * 8;
            uint4 v = *(const uint4*)src;
            *(uint4*)&As[buf][((r >> 4) * 64 + jj * 16 + (r & 15)) * 8] = v;
            *(uint4*)&Seq[r * 264 + kt * 32 + jj * 8] = v;
        }
        {
            const unsigned short* src = W2pk + (size_t)kt * 16 * 512;
            #pragma unroll
            for (int u = 0; u < 4; ++u) {
                int sg = wid * 4 + u;
                gl_lds16(src + sg * 512 + lane * 8, &Bs[buf][sg * 512]);
            }
        }
    };

    floatx4 acc[4][4] = {};
    stage(0, 0);
    {   // q1[d] = sum_k ht[k]*W1[k][d] + b1[d]   (f32) — overlaps stage(0) latency
        float q0 = 0, q1v = 0, q2v = 0, q3v = 0;
        for (int k = 0; k < 256; k += 4) {
            q0  = fmaf(hts[k],     W1[(size_t)k * 256 + tid],       q0);
            q1v = fmaf(hts[k + 1], W1[(size_t)(k + 1) * 256 + tid], q1v);
            q2v = fmaf(hts[k + 2], W1[(size_t)(k + 2) * 256 + tid], q2v);
            q3v = fmaf(hts[k + 3], W1[(size_t)(k + 3) * 256 + tid], q3v);
        }
        q1s[tid] = (q0 + q1v) + (q2v + q3v) + b1[tid];
    }
    __syncthreads();
    #pragma unroll
    for (int kt = 0; kt < 8; ++kt) {
        int cur = kt & 1;
        if (kt < 7) stage(kt + 1, cur ^ 1);
        bhalf8 a[4], bb[4];
        #pragma unroll
        for (int i = 0; i < 4; i++) a[i] = *(const bhalf8*)&As[cur][(i * 64 + lane) * 8];
        #pragma unroll
        for (int j = 0; j < 4; j++) bb[j] = *(const bhalf8*)&Bs[cur][((wid * 4 + j) * 64 + lane) * 8];
        #pragma unroll
        for (int i = 0; i < 4; i++)
            #pragma unroll
            for (int j = 0; j < 4; j++) acc[i][j] = mfma16(a[i], bb[j], acc[i][j]);
        __syncthreads();
    }
    float q1v[4], b2v[4], w3v[4];
    #pragma unroll
    for (int j = 0; j < 4; j++) {
        int col = wid * 64 + j * 16 + (lane & 15);
        q1v[j] = q1s[col];
        b2v[j] = b2[col];
        w3v[j] = W3[col];
    }
    #pragma unroll
    for (int i = 0; i < 4; i++) {
        #pragma unroll
        for (int reg = 0; reg < 4; reg++) {
            float t = 0.f;
            #pragma unroll
            for (int j = 0; j < 4; j++)
                t += sigmoidf_(acc[i][j][reg] + q1v[j] + b2v[j]) * w3v[j];
            #pragma unroll
            for (int off = 1; off < 16; off <<= 1) t += __shfl_xor(t, off);
            if ((lane & 15) == 0) alphap[wid][i * 16 + (lane >> 4) * 4 + reg] = t;
        }
    }
    __syncthreads();
    if (tid < 64) {
        float al = alphap[0][tid] + alphap[1][tid] + alphap[2][tid] + alphap[3][tid];
        am[tid] = al * (float)mask[b * 64 + tid];
    }
    __syncthreads();
    float acca = 0.f;
    #pragma unroll 8
    for (int l = 0; l < 64; ++l)
        acca = fmaf(am[l], bf2f(Seq[l * 264 + tid]), acca);
    a_bf[(size_t)b * 256 + tid] = f2bf(acca);
}

// ---------------------------------------------------------------------------
// K6: fused final MLP, BK=64 (R14-proven form).
// BM=64, 8 blocks; y kept in LDS in A-fragment layout.
// ---------------------------------------------------------------------------
__global__ __launch_bounds__(256) void mlp_fused(
    const unsigned short* __restrict__ a_bf, const unsigned short* __restrict__ ht_bf,
    const unsigned short* __restrict__ Wn1pk, const float* __restrict__ bn1,
    const unsigned short* __restrict__ Wn2pk, const float* __restrict__ bn2,
    float* __restrict__ out)
{
    __shared__ unsigned short As[4096];     // 2 kt x 4 m-frags
    __shared__ unsigned short Bs[16384];    // 2 kt x 16 n-frags
    __shared__ unsigned short Ys[16384];    // y (64 x 256) A-frag layout
    const int tid = threadIdx.x;
    const int wid = tid >> 6, lane = tid & 63;
    const int bm = blockIdx.x * 64;
    const int c = lane & 15;
    const int r0 = (lane >> 4) * 4;

    {
        floatx4 acc[4][4] = {};
        #pragma unroll
        for (int s = 0; s < 8; ++s) {
            #pragma unroll
            for (int v = 0; v < 2; ++v) {
                int kt = s * 2 + v;
                int r = tid >> 2, jj = tid & 3;
                const unsigned short* src = ((kt < 8) ? a_bf : ht_bf)
                    + (size_t)(bm + r) * 256 + (kt & 7) * 32 + jj * 8;
                *(uint4*)&As[v * 2048 + ((r >> 4) * 64 + jj * 16 + (r & 15)) * 8] = *(const uint4*)src;
            }
            #pragma unroll
            for (int u = 0; u < 8; ++u) {
                int sg = wid * 8 + u;
                int ktl = sg >> 4, f = sg & 15;
                gl_lds16(Wn1pk + ((size_t)(s * 2 + ktl) * 16 + f) * 512 + lane * 8, &Bs[sg * 512]);
            }
            __syncthreads();
            #pragma unroll
            for (int v = 0; v < 2; ++v) {
                bhalf8 a[4], bb[4];
                #pragma unroll
                for (int i = 0; i < 4; i++) a[i] = *(const bhalf8*)&As[v * 2048 + (i * 64 + lane) * 8];
                #pragma unroll
                for (int j = 0; j < 4; j++) bb[j] = *(const bhalf8*)&Bs[((v * 16) + wid * 4 + j) * 512 + lane * 8];
                #pragma unroll
                for (int i = 0; i < 4; i++)
                    #pragma unroll
                    for (int j = 0; j < 4; j++) acc[i][j] = mfma16(a[i], bb[j], acc[i][j]);
            }
            __syncthreads();
        }
        #pragma unroll
        for (int i = 0; i < 4; i++) {
            #pragma unroll
            for (int jf = 0; jf < 4; jf++) {
                int n = wid * 64 + jf * 16 + c;
                float bv = bn1[n];
                int kt2 = wid * 2 + (jf >> 1);
                int l2 = ((jf & 1) * 2 + (c >> 3)) * 16;
                #pragma unroll
                for (int reg = 0; reg < 4; reg++) {
                    float v = fmaxf(acc[i][jf][reg] + bv, 0.f);
                    size_t idx = (((size_t)(kt2 * 4 + i) * 64) + l2 + r0 + reg) * 8 + (c & 7);
                    Ys[idx] = f2bf(v);
                }
            }
        }
    }
    __syncthreads();
    floatx4 acc2[4][4] = {};
    #pragma unroll
    for (int s = 0; s < 4; ++s) {
        #pragma unroll
        for (int u = 0; u < 8; ++u) {
            int sg = wid * 8 + u;
            int ktl = sg >> 4, f = sg & 15;
            gl_lds16(Wn2pk + ((size_t)(s * 2 + ktl) * 16 + f) * 512 + lane * 8, &Bs[sg * 512]);
        }
        __syncthreads();
        #pragma unroll
        for (int v = 0; v < 2; ++v) {
            int kt2 = s * 2 + v;
            bhalf8 a[4], bb[4];
            #pragma unroll
            for (int i = 0; i < 4; i++) a[i] = *(const bhalf8*)&Ys[((kt2 * 4 + i) * 64 + lane) * 8];
            #pragma unroll
            for (int j = 0; j < 4; j++) bb[j] = *(const bhalf8*)&Bs[((v * 16) + wid * 4 + j) * 512 + lane * 8];
            #pragma unroll
            for (int i = 0; i < 4; i++)
                #pragma unroll
                for (int j = 0; j < 4; j++) acc2[i][j] = mfma16(a[i], bb[j], acc2[i][j]);
        }
        __syncthreads();
    }
    #pragma unroll
    for (int i = 0; i < 4; i++) {
        #pragma unroll
        for (int jf = 0; jf < 4; jf++) {
            int n = wid * 64 + jf * 16 + c;
            float bv = bn2[n];
            #pragma unroll
            for (int reg = 0; reg < 4; reg++) {
                int m = bm + i * 16 + r0 + reg;
                out[(size_t)m * 256 + n] = acc2[i][jf][reg] + bv;
            }
        }
    }
}

// ---------------------------------------------------------------------------
extern "C" void kernel_launch(void* const* d_in, const int* in_sizes, int n_in,
                              void* d_out, int out_size, void* d_ws, size_t ws_size,
                              hipStream_t stream)
{
    const int*   alias  = (const int*)  d_in[0];
    const float* A      = (const float*)d_in[1];
    const int*   items  = (const int*)  d_in[2];
    const int*   mask   = (const int*)  d_in[3];
    const float* emb    = (const float*)d_in[4];
    const float* W_ein  = (const float*)d_in[5];
    const float* b_ein  = (const float*)d_in[6];
    const float* W_eout = (const float*)d_in[7];
    const float* b_eout = (const float*)d_in[8];
    const float* b_iah  = (const float*)d_in[9];
    const float* b_oah  = (const float*)d_in[10];
    const float* W_i    = (const float*)d_in[11];
    const float* b_i    = (const float*)d_in[12];
    const float* W_h    = (const float*)d_in[13];
    const float* b_h    = (const float*)d_in[14];
    const float* W1     = (const float*)d_in[15];
    const float* b1     = (const float*)d_in[16];
    const float* W2     = (const float*)d_in[17];
    const float* b2     = (const float*)d_in[18];
    const float* W3     = (const float*)d_in[19];
    const float* Wn1    = (const float*)d_in[20];
    const float* bn1    = (const float*)d_in[21];
    const float* Wn2    = (const float*)d_in[22];
    const float* bn2    = (const float*)d_in[23];
    float* out = (float*)d_out;
    (void)in_sizes; (void)n_in; (void)out_size; (void)ws_size;

    char* w = (char*)d_ws;
    unsigned short* hidden_pk = (unsigned short*)(w);                 // 16,777,216
    unsigned short* inp_pk    = (unsigned short*)(w + 50331648);      // 33,554,432
    unsigned short* newh_bf   = (unsigned short*)(w + 83886080);      // 16,777,216
    unsigned short* Wio_pk    = (unsigned short*)(w + 100663296);     //    262,144
    unsigned short* Wg_pk     = (unsigned short*)(w + 100925440);     //  1,179,648
    unsigned short* W2pk      = (unsigned short*)(w + 102105088);     //    131,072
    unsigned short* Wn1pk     = (unsigned short*)(w + 102236160);     //    262,144
    unsigned short* Wn2pk     = (unsigned short*)(w + 102498304);     //    131,072
    unsigned short* ht_bf     = (unsigned short*)(w + 102629376);     //    262,144
    unsigned short* a_bf      = (unsigned short*)(w + 102891520);     //    262,144

    pack_all   <<<7936, 256, 0, stream>>>(W_ein, W_eout, W_i, W_h, W2, Wn1, Wn2,
                                          items, emb,
                                          Wio_pk, Wg_pk, W2pk, Wn1pk, Wn2pk, hidden_pk);
    gemm_hioadj<<<dim3(256, 4), 256, 0, stream>>>(hidden_pk, Wio_pk, b_ein, b_eout,
                                                  A, b_iah, b_oah, inp_pk);
    gru_mfma   <<<dim3(256, 4), 256, 0, stream>>>(inp_pk, hidden_pk, Wg_pk, b_i, b_h, newh_bf);
    attn_fused <<<512, 256, 0, stream>>>(newh_bf, alias, mask, W1, b1, b2, W3, W2pk, ht_bf, a_bf);
    mlp_fused  <<<8, 256, 0, stream>>>(a_bf, ht_bf, Wn1pk, bn1, Wn2pk, bn2, out);
}

// Round 19
// 136.498 us; speedup vs baseline: 1.0488x; 1.0038x over previous
//
#include <hip/hip_runtime.h>
#include <hip/hip_bf16.h>
#include <math.h>

typedef short bhalf8 __attribute__((ext_vector_type(8)));
typedef float floatx4 __attribute__((ext_vector_type(4)));

__device__ __forceinline__ float sigmoidf_(float x) { return 1.0f / (1.0f + __expf(-x)); }

__device__ __forceinline__ unsigned short f2bf(float f) {
    unsigned int u = __builtin_bit_cast(unsigned int, f);
    u += 0x7FFFu + ((u >> 16) & 1u);
    return (unsigned short)(u >> 16);
}
__device__ __forceinline__ float bf2f(unsigned short h) {
    unsigned int u = ((unsigned int)h) << 16;
    return __builtin_bit_cast(float, u);
}

__device__ __forceinline__ floatx4 mfma16(bhalf8 a, bhalf8 b, floatx4 c) {
    return __builtin_amdgcn_mfma_f32_16x16x32_bf16(a, b, c, 0, 0, 0);
}

// async global->LDS, 16B/lane: LDS dest = wave-uniform base + lane*16.
__device__ __forceinline__ void gl_lds16(const unsigned short* g, unsigned short* l) {
    __builtin_amdgcn_global_load_lds(
        (const __attribute__((address_space(1))) void*)g,
        (__attribute__((address_space(3))) void*)l, 16, 0, 0);
}

// ---------------------------------------------------------------------------
// pack helpers: f32 [K][N] -> bf16 B-fragment-linear tiles.
// ---------------------------------------------------------------------------
__device__ __forceinline__ void pack_generic(
    int b, int tid, const float* __restrict__ W0, const float* __restrict__ W1,
    int split, int N, int BN, unsigned short* __restrict__ out)
{
    int t = b * 256 + tid;
    int j = t & 7;
    int lane = (t >> 3) & 63;
    int FT = BN >> 4;
    int f = (t >> 9) % FT;
    int rest = t / (512 * FT);
    int NT = N / BN;
    int nt = rest % NT;
    int kt = rest / NT;
    int k = kt * 32 + (lane >> 4) * 8 + j;
    int n = nt * BN + f * 16 + (lane & 15);
    float v = (n < split) ? W0[(size_t)k * split + n]
                          : W1[(size_t)k * (N - split) + (n - split)];
    out[t] = f2bf(v);
}

// combined GRU pack: Wcat[768][768] = [W_i ; W_h]
__device__ __forceinline__ void pack_gru_(
    int b, int tid, const float* __restrict__ Wi, const float* __restrict__ Wh,
    unsigned short* __restrict__ out)
{
    int t = b * 256 + tid;
    int j = t & 7;
    int lane = (t >> 3) & 63;
    int f = (t >> 9) & 3;
    int q = t >> 11;
    int g = q % 3;
    int p = q / 3;
    int dt = p & 3;
    int kt = p >> 2;
    int k = kt * 32 + (lane >> 4) * 8 + j;
    int n = g * 256 + dt * 64 + f * 16 + (lane & 15);
    float v = (k < 512) ? Wi[(size_t)k * 768 + n] : Wh[(size_t)(k - 512) * 768 + n];
    out[t] = f2bf(v);
}

// P0: all weight packs + embedding gather in ONE launch (7936 blocks).
// Gather branch: 32 threads per emb row -> fully coalesced 1KB row reads;
// each thread packs its 8-float chunk (k&7==0) as one uint4 to hidden_pk.
__global__ __launch_bounds__(256) void pack_all(
    const float* __restrict__ W_ein, const float* __restrict__ W_eout,
    const float* __restrict__ Wi, const float* __restrict__ Wh,
    const float* __restrict__ W2, const float* __restrict__ Wn1,
    const float* __restrict__ Wn2,
    const int* __restrict__ items, const float* __restrict__ emb,
    unsigned short* __restrict__ Wio_pk, unsigned short* __restrict__ Wg_pk,
    unsigned short* __restrict__ W2pk, unsigned short* __restrict__ Wn1pk,
    unsigned short* __restrict__ Wn2pk, unsigned short* __restrict__ hidden_pk)
{
    int bx = blockIdx.x;
    int tid = threadIdx.x;
    if (bx < 512)       { pack_generic(bx,        tid, W_ein, W_eout, 256, 512, 128, Wio_pk); return; }
    if (bx < 2816)      { pack_gru_   (bx - 512,  tid, Wi, Wh, Wg_pk); return; }
    if (bx < 3072)      { pack_generic(bx - 2816, tid, W2,  W2,  256, 256, 256, W2pk); return; }
    if (bx < 3584)      { pack_generic(bx - 3072, tid, Wn1, Wn1, 256, 256, 256, Wn1pk); return; }
    if (bx < 3840)      { pack_generic(bx - 3584, tid, Wn2, Wn2, 256, 256, 256, Wn2pk); return; }
    // gather: hidden_pk = bf16(emb[items]) in A-fragment-packed layout.
    {
        int g = bx - 3840;                 // 4096 blocks x 8 rows
        int m = g * 8 + (tid >> 5);        // row
        int kk = (tid & 31) * 8;           // 8-float chunk within row
        int it = items[m];
        const float* src = emb + (size_t)it * 256 + kk;
        float4 v0 = *(const float4*)src;
        float4 v1 = *(const float4*)(src + 4);
        uint4 o;
        o.x = f2bf(v0.x) | ((unsigned)f2bf(v0.y) << 16);
        o.y = f2bf(v0.z) | ((unsigned)f2bf(v0.w) << 16);
        o.z = f2bf(v1.x) | ((unsigned)f2bf(v1.y) << 16);
        o.w = f2bf(v1.z) | ((unsigned)f2bf(v1.w) << 16);
        size_t idx = (((size_t)(m >> 4) * 8 + (kk >> 5)) * 64
                      + ((kk >> 3) & 3) * 16 + (m & 15)) * 8;
        *(uint4*)(hidden_pk + idx) = o;
    }
}

// ---------------------------------------------------------------------------
// K2: FUSED hio + adjacency (R15-proven form).
// ---------------------------------------------------------------------------
__global__ __launch_bounds__(256) void gemm_hioadj(
    const unsigned short* __restrict__ hidden_pk,
    const unsigned short* __restrict__ Wio_pk,
    const float* __restrict__ bein, const float* __restrict__ beout,
    const float* __restrict__ A,
    const float* __restrict__ biah, const float* __restrict__ boah,
    unsigned short* __restrict__ inp_pk)
{
    __shared__ unsigned short SM[24576];   // 48KB
    unsigned short* As0 = SM;              // phase1 A dbuf [2][4096]
    unsigned short* Bs0 = SM + 8192;       // phase1 B dbuf [2][4096]
    unsigned short* Hb  = SM;              // phase2 hio tile (overlaps, 16384)
    unsigned short* Ab  = SM + 16384;      // phase2 adjacency frags (8192)

    const int tid = threadIdx.x;
    const int wid = tid >> 6, lane = tid & 63;
    const int wr = wid >> 1, wc = wid & 1;
    const int bm = blockIdx.x * 128;
    const int nt = blockIdx.y;
    const int mg0 = bm >> 4;
    const int b0 = blockIdx.x * 2;
    const int half = nt >> 1;

    auto stage = [&](int kt, int buf) {
        #pragma unroll
        for (int u = 0; u < 2; ++u) {
            int rg = wid * 2 + u;
            gl_lds16(hidden_pk + ((size_t)(mg0 + rg) * 8 + kt) * 512 + lane * 8,
                     &As0[buf * 4096 + rg * 512]);
            gl_lds16(Wio_pk + ((size_t)(kt * 4 + nt) * 8 + rg) * 512 + lane * 8,
                     &Bs0[buf * 4096 + rg * 512]);
        }
    };

    floatx4 acc[4][4] = {};
    stage(0, 0);
    __syncthreads();
    #pragma unroll
    for (int kt = 0; kt < 8; ++kt) {
        int cur = kt & 1;
        if (kt < 7) stage(kt + 1, cur ^ 1);
        bhalf8 a[4], b[4];
        #pragma unroll
        for (int i = 0; i < 4; i++) a[i] = *(const bhalf8*)&As0[cur * 4096 + (wr * 4 + i) * 512 + lane * 8];
        #pragma unroll
        for (int j = 0; j < 4; j++) b[j] = *(const bhalf8*)&Bs0[cur * 4096 + (wc * 4 + j) * 512 + lane * 8];
        #pragma unroll
        for (int i = 0; i < 4; i++)
            #pragma unroll
            for (int j = 0; j < 4; j++) acc[i][j] = mfma16(a[i], b[j], acc[i][j]);
        __syncthreads();
    }
    const int r0 = (lane >> 4) * 4;
    // Epilogue 1: bias + pack into LDS Hb (B-fragment layout).
    {
        const float* bio = half ? beout : bein;
        #pragma unroll
        for (int mf = 0; mf < 4; mf++) {
            #pragma unroll
            for (int nf = 0; nf < 4; nf++) {
                int nl = wc * 64 + nf * 16 + (lane & 15);
                float bias = bio[(nt & 1) * 128 + nl];
                int base = (((wr * 2 + (mf >> 1)) * 8 + (nl >> 4)) * 64
                            + ((mf & 1) * 2 + (r0 >> 3)) * 16 + (lane & 15)) * 8 + (r0 & 7);
                ushort4 o;
                o.x = f2bf(acc[mf][nf][0] + bias);
                o.y = f2bf(acc[mf][nf][1] + bias);
                o.z = f2bf(acc[mf][nf][2] + bias);
                o.w = f2bf(acc[mf][nf][3] + bias);
                *(ushort4*)&Hb[base] = o;
            }
        }
    }
    // Stage adjacency A-frags for both batches (f32->bf16).
    {
        int r = tid >> 2, jj = tid & 3;
        #pragma unroll
        for (int bb = 0; bb < 2; ++bb)
            #pragma unroll
            for (int kt2 = 0; kt2 < 2; ++kt2) {
                const float* src = A + (size_t)(b0 + bb) * 8192 + r * 128 + half * 64 + kt2 * 32 + jj * 8;
                float4 v0 = *(const float4*)src;
                float4 v1 = *(const float4*)(src + 4);
                uint4 o;
                o.x = f2bf(v0.x) | ((unsigned)f2bf(v0.y) << 16);
                o.y = f2bf(v0.z) | ((unsigned)f2bf(v0.w) << 16);
                o.z = f2bf(v1.x) | ((unsigned)f2bf(v1.y) << 16);
                o.w = f2bf(v1.z) | ((unsigned)f2bf(v1.w) << 16);
                *(uint4*)&Ab[(bb * 2 + kt2) * 2048 + ((r >> 4) * 64 + jj * 16 + (r & 15)) * 8] = o;
            }
    }
    __syncthreads();
    // Phase 2: wave handles batch bb = wid>>1, col-half ch = wid&1.
    const int bb = wid >> 1, ch = wid & 1;
    floatx4 acc2[4][4] = {};
    #pragma unroll
    for (int kt2 = 0; kt2 < 2; ++kt2) {
        bhalf8 a2[4];
        #pragma unroll
        for (int i = 0; i < 4; i++)
            a2[i] = *(const bhalf8*)&Ab[(bb * 2 + kt2) * 2048 + (i * 64 + lane) * 8];
        #pragma unroll
        for (int jf = 0; jf < 4; jf++) {
            bhalf8 bv = *(const bhalf8*)&Hb[((bb * 2 + kt2) * 8 + ch * 4 + jf) * 512 + lane * 8];
            #pragma unroll
            for (int i = 0; i < 4; i++) acc2[i][jf] = mfma16(a2[i], bv, acc2[i][jf]);
        }
    }
    // Epilogue 2: write inp_pk (A-frag packed).
    {
        const float* bia = half ? boah : biah;
        const int b = b0 + bb;
        #pragma unroll
        for (int i = 0; i < 4; i++) {
            #pragma unroll
            for (int jf = 0; jf < 4; jf++) {
                int colp = (nt & 1) * 128 + (ch * 4 + jf) * 16 + (lane & 15);
                float bv = bia[colp];
                int kt5 = nt * 4 + ch * 2 + (jf >> 1);
                int l2 = ((jf & 1) * 2 + ((lane >> 3) & 1)) * 16;
                #pragma unroll
                for (int reg = 0; reg < 4; reg++) {
                    int mlo = r0 + reg;
                    size_t dst = (((size_t)(b * 4 + i) * 16 + kt5) * 64 + l2 + mlo) * 8 + (lane & 7);
                    inp_pk[dst] = f2bf(acc2[i][jf][reg] + bv);
                }
            }
        }
    }
}

// ---------------------------------------------------------------------------
// K4: GRU cell v9 (R11/R14-proven, byte-exact): counted-vmcnt pipeline
// (A 3-deep / B 2-deep), fully unrolled, wave = 64 rows x 32 d,
// grid (256,4) x 256 thr.  Epilogue untouched (R12/R13 cliffs).
// ---------------------------------------------------------------------------
__global__ __launch_bounds__(256) void gru_mfma(
    const unsigned short* __restrict__ inp_pk,
    const unsigned short* __restrict__ hidden_pk,
    const unsigned short* __restrict__ Wg_pk,
    const float* __restrict__ bi, const float* __restrict__ bh,
    unsigned short* __restrict__ newh_bf)
{
    __shared__ unsigned short As3[3][4096];    // 24KB
    __shared__ unsigned short Bs2[2][6144];    // 12KB
    const int tid = threadIdx.x;
    const int wid = tid >> 6, lane = tid & 63;
    const int wr = wid >> 1, wc = wid & 1;
    const int bm = blockIdx.x * 128;
    const int dt = blockIdx.y;
    const int mg0 = bm >> 4;

    floatx4 R[4][2] = {}, I[4][2] = {}, N0[4][2] = {}, N1[4][2] = {};

    auto stageA = [&](int st, int buf) {
        #pragma unroll
        for (int u = 0; u < 2; ++u) {
            int rg = wid * 2 + u;
            const unsigned short* src = (st < 16)
                ? inp_pk    + ((size_t)(mg0 + rg) * 16 + st) * 512
                : hidden_pk + ((size_t)(mg0 + rg) * 8 + (st - 16)) * 512;
            gl_lds16(src + lane * 8, &As3[buf][rg * 512]);
        }
    };
    auto stageB = [&](int st, int buf) {
        #pragma unroll
        for (int u = 0; u < 3; ++u) {
            int sg = wid * 3 + u;
            gl_lds16(Wg_pk + ((size_t)(st * 4 + dt) * 12 + sg) * 512 + lane * 8,
                     &Bs2[buf][sg * 512]);
        }
    };

    // prologue issue order matters for vmcnt counting: A0, B0, A1
    stageA(0, 0);
    stageB(0, 0);
    stageA(1, 1);
    #pragma unroll
    for (int st = 0; st < 24; ++st) {
        const int ca = st % 3, cb = st & 1;
        if (st < 23) asm volatile("s_waitcnt vmcnt(2)" ::: "memory");
        else         asm volatile("s_waitcnt vmcnt(0)" ::: "memory");
        __builtin_amdgcn_s_barrier();
        __builtin_amdgcn_sched_barrier(0);
        if (st < 23) stageB(st + 1, cb ^ 1);
        if (st < 22) stageA(st + 2, (st + 2) % 3);
        bhalf8 a[4];
        #pragma unroll
        for (int i = 0; i < 4; i++)
            a[i] = *(const bhalf8*)&As3[ca][(wr * 4 + i) * 512 + lane * 8];
        #pragma unroll
        for (int f = 0; f < 2; ++f) {
            bhalf8 bv = *(const bhalf8*)&Bs2[cb][(0 * 4 + wc * 2 + f) * 512 + lane * 8];
            #pragma unroll
            for (int i = 0; i < 4; i++) R[i][f] = mfma16(a[i], bv, R[i][f]);
        }
        #pragma unroll
        for (int f = 0; f < 2; ++f) {
            bhalf8 bv = *(const bhalf8*)&Bs2[cb][(1 * 4 + wc * 2 + f) * 512 + lane * 8];
            #pragma unroll
            for (int i = 0; i < 4; i++) I[i][f] = mfma16(a[i], bv, I[i][f]);
        }
        if (st < 16) {
            #pragma unroll
            for (int f = 0; f < 2; ++f) {
                bhalf8 bv = *(const bhalf8*)&Bs2[cb][(2 * 4 + wc * 2 + f) * 512 + lane * 8];
                #pragma unroll
                for (int i = 0; i < 4; i++) N0[i][f] = mfma16(a[i], bv, N0[i][f]);
            }
        } else {
            #pragma unroll
            for (int f = 0; f < 2; ++f) {
                bhalf8 bv = *(const bhalf8*)&Bs2[cb][(2 * 4 + wc * 2 + f) * 512 + lane * 8];
                #pragma unroll
                for (int i = 0; i < 4; i++) N1[i][f] = mfma16(a[i], bv, N1[i][f]);
            }
        }
    }
    // Gates epilogue: wave owns rows [bm+wr*64, +64), d [dt*64+wc*32, +32)
    const int r0 = (lane >> 4) * 4;
    const int bd = dt * 64 + wc * 32;
    #pragma unroll
    for (int i = 0; i < 4; i++) {
        #pragma unroll
        for (int f = 0; f < 2; f++) {
            int d = bd + f * 16 + (lane & 15);
            float bir = bi[d] + bh[d];
            float bii = bi[256 + d] + bh[256 + d];
            float bin = bi[512 + d];
            float bhn = bh[512 + d];
            #pragma unroll
            for (int reg = 0; reg < 4; reg++) {
                int m = bm + wr * 64 + i * 16 + r0 + reg;
                size_t hidx = (((size_t)(m >> 4) * 8 + (d >> 5)) * 64
                               + ((d >> 3) & 3) * 16 + (m & 15)) * 8 + (d & 7);
                float hv = bf2f(hidden_pk[hidx]);
                float rg = sigmoidf_(R[i][f][reg] + bir);
                float ig = sigmoidf_(I[i][f][reg] + bii);
                float ng = tanhf(N0[i][f][reg] + bin + rg * (N1[i][f][reg] + bhn));
                newh_bf[(size_t)m * 256 + d] = f2bf(ng + ig * (hv - ng));
            }
        }
    }
}

// ---------------------------------------------------------------------------
// K5: fused attention (R18-proven form): ht in-block, 2-phase dbuf kt-loop,
// Seq row-major LDS copy for the final a-accumulation.
// ---------------------------------------------------------------------------
__global__ __launch_bounds__(256) void attn_fused(
    const unsigned short* __restrict__ newh_bf,
    const int* __restrict__ alias, const int* __restrict__ mask,
    const float* __restrict__ W1, const float* __restrict__ b1,
    const float* __restrict__ b2, const float* __restrict__ W3,
    const unsigned short* __restrict__ W2pk,
    unsigned short* __restrict__ ht_bf,
    unsigned short* __restrict__ a_bf)
{
    const int b = blockIdx.x;
    const int tid = threadIdx.x;
    const int wid = tid >> 6, lane = tid & 63;
    __shared__ int arow[64];
    __shared__ int node_s;
    __shared__ float hts[256];
    __shared__ float q1s[256];
    __shared__ float alphap[4][64];
    __shared__ float am[64];
    __shared__ unsigned short As[2][2048];
    __shared__ unsigned short Bs[2][8192];
    __shared__ unsigned short Seq[64 * 264];   // row-major, pad 8
    if (tid < 64) {
        arow[tid] = b * 64 + alias[b * 64 + tid];
        int mv = mask[b * 64 + tid];
        #pragma unroll
        for (int off = 32; off > 0; off >>= 1) mv += __shfl_xor(mv, off);
        if (tid == 0) node_s = b * 64 + alias[b * 64 + (mv - 1)];
    }
    __syncthreads();
    {
        unsigned short hv = newh_bf[(size_t)node_s * 256 + tid];
        ht_bf[(size_t)b * 256 + tid] = hv;
        hts[tid] = bf2f(hv);
    }
    __syncthreads();

    auto stage = [&](int kt, int buf) {
        {
            int r = tid >> 2, jj = tid & 3;
            const unsigned short* src = newh_bf + (size_t)arow[r] * 256 + kt * 32 + jj * 8;
            uint4 v = *(const uint4*)src;
            *(uint4*)&As[buf][((r >> 4) * 64 + jj * 16 + (r & 15)) * 8] = v;
            *(uint4*)&Seq[r * 264 + kt * 32 + jj * 8] = v;
        }
        {
            const unsigned short* src = W2pk + (size_t)kt * 16 * 512;
            #pragma unroll
            for (int u = 0; u < 4; ++u) {
                int sg = wid * 4 + u;
                gl_lds16(src + sg * 512 + lane * 8, &Bs[buf][sg * 512]);
            }
        }
    };

    floatx4 acc[4][4] = {};
    stage(0, 0);
    {   // q1[d] = sum_k ht[k]*W1[k][d] + b1[d]   (f32) — overlaps stage(0) latency
        float q0 = 0, q1v = 0, q2v = 0, q3v = 0;
        for (int k = 0; k < 256; k += 4) {
            q0  = fmaf(hts[k],     W1[(size_t)k * 256 + tid],       q0);
            q1v = fmaf(hts[k + 1], W1[(size_t)(k + 1) * 256 + tid], q1v);
            q2v = fmaf(hts[k + 2], W1[(size_t)(k + 2) * 256 + tid], q2v);
            q3v = fmaf(hts[k + 3], W1[(size_t)(k + 3) * 256 + tid], q3v);
        }
        q1s[tid] = (q0 + q1v) + (q2v + q3v) + b1[tid];
    }
    __syncthreads();
    #pragma unroll
    for (int kt = 0; kt < 8; ++kt) {
        int cur = kt & 1;
        if (kt < 7) stage(kt + 1, cur ^ 1);
        bhalf8 a[4], bb[4];
        #pragma unroll
        for (int i = 0; i < 4; i++) a[i] = *(const bhalf8*)&As[cur][(i * 64 + lane) * 8];
        #pragma unroll
        for (int j = 0; j < 4; j++) bb[j] = *(const bhalf8*)&Bs[cur][((wid * 4 + j) * 64 + lane) * 8];
        #pragma unroll
        for (int i = 0; i < 4; i++)
            #pragma unroll
            for (int j = 0; j < 4; j++) acc[i][j] = mfma16(a[i], bb[j], acc[i][j]);
        __syncthreads();
    }
    float q1v[4], b2v[4], w3v[4];
    #pragma unroll
    for (int j = 0; j < 4; j++) {
        int col = wid * 64 + j * 16 + (lane & 15);
        q1v[j] = q1s[col];
        b2v[j] = b2[col];
        w3v[j] = W3[col];
    }
    #pragma unroll
    for (int i = 0; i < 4; i++) {
        #pragma unroll
        for (int reg = 0; reg < 4; reg++) {
            float t = 0.f;
            #pragma unroll
            for (int j = 0; j < 4; j++)
                t += sigmoidf_(acc[i][j][reg] + q1v[j] + b2v[j]) * w3v[j];
            #pragma unroll
            for (int off = 1; off < 16; off <<= 1) t += __shfl_xor(t, off);
            if ((lane & 15) == 0) alphap[wid][i * 16 + (lane >> 4) * 4 + reg] = t;
        }
    }
    __syncthreads();
    if (tid < 64) {
        float al = alphap[0][tid] + alphap[1][tid] + alphap[2][tid] + alphap[3][tid];
        am[tid] = al * (float)mask[b * 64 + tid];
    }
    __syncthreads();
    float acca = 0.f;
    #pragma unroll 8
    for (int l = 0; l < 64; ++l)
        acca = fmaf(am[l], bf2f(Seq[l * 264 + tid]), acca);
    a_bf[(size_t)b * 256 + tid] = f2bf(acca);
}

// ---------------------------------------------------------------------------
// K6: fused final MLP, BK=64 (R14-proven form).
// BM=64, 8 blocks; y kept in LDS in A-fragment layout.
// ---------------------------------------------------------------------------
__global__ __launch_bounds__(256) void mlp_fused(
    const unsigned short* __restrict__ a_bf, const unsigned short* __restrict__ ht_bf,
    const unsigned short* __restrict__ Wn1pk, const float* __restrict__ bn1,
    const unsigned short* __restrict__ Wn2pk, const float* __restrict__ bn2,
    float* __restrict__ out)
{
    __shared__ unsigned short As[4096];     // 2 kt x 4 m-frags
    __shared__ unsigned short Bs[16384];    // 2 kt x 16 n-frags
    __shared__ unsigned short Ys[16384];    // y (64 x 256) A-frag layout
    const int tid = threadIdx.x;
    const int wid = tid >> 6, lane = tid & 63;
    const int bm = blockIdx.x * 64;
    const int c = lane & 15;
    const int r0 = (lane >> 4) * 4;

    {
        floatx4 acc[4][4] = {};
        #pragma unroll
        for (int s = 0; s < 8; ++s) {
            #pragma unroll
            for (int v = 0; v < 2; ++v) {
                int kt = s * 2 + v;
                int r = tid >> 2, jj = tid & 3;
                const unsigned short* src = ((kt < 8) ? a_bf : ht_bf)
                    + (size_t)(bm + r) * 256 + (kt & 7) * 32 + jj * 8;
                *(uint4*)&As[v * 2048 + ((r >> 4) * 64 + jj * 16 + (r & 15)) * 8] = *(const uint4*)src;
            }
            #pragma unroll
            for (int u = 0; u < 8; ++u) {
                int sg = wid * 8 + u;
                int ktl = sg >> 4, f = sg & 15;
                gl_lds16(Wn1pk + ((size_t)(s * 2 + ktl) * 16 + f) * 512 + lane * 8, &Bs[sg * 512]);
            }
            __syncthreads();
            #pragma unroll
            for (int v = 0; v < 2; ++v) {
                bhalf8 a[4], bb[4];
                #pragma unroll
                for (int i = 0; i < 4; i++) a[i] = *(const bhalf8*)&As[v * 2048 + (i * 64 + lane) * 8];
                #pragma unroll
                for (int j = 0; j < 4; j++) bb[j] = *(const bhalf8*)&Bs[((v * 16) + wid * 4 + j) * 512 + lane * 8];
                #pragma unroll
                for (int i = 0; i < 4; i++)
                    #pragma unroll
                    for (int j = 0; j < 4; j++) acc[i][j] = mfma16(a[i], bb[j], acc[i][j]);
            }
            __syncthreads();
        }
        #pragma unroll
        for (int i = 0; i < 4; i++) {
            #pragma unroll
            for (int jf = 0; jf < 4; jf++) {
                int n = wid * 64 + jf * 16 + c;
                float bv = bn1[n];
                int kt2 = wid * 2 + (jf >> 1);
                int l2 = ((jf & 1) * 2 + (c >> 3)) * 16;
                #pragma unroll
                for (int reg = 0; reg < 4; reg++) {
                    float v = fmaxf(acc[i][jf][reg] + bv, 0.f);
                    size_t idx = (((size_t)(kt2 * 4 + i) * 64) + l2 + r0 + reg) * 8 + (c & 7);
                    Ys[idx] = f2bf(v);
                }
            }
        }
    }
    __syncthreads();
    floatx4 acc2[4][4] = {};
    #pragma unroll
    for (int s = 0; s < 4; ++s) {
        #pragma unroll
        for (int u = 0; u < 8; ++u) {
            int sg = wid * 8 + u;
            int ktl = sg >> 4, f = sg & 15;
            gl_lds16(Wn2pk + ((size_t)(s * 2 + ktl) * 16 + f) * 512 + lane * 8, &Bs[sg * 512]);
        }
        __syncthreads();
        #pragma unroll
        for (int v = 0; v < 2; ++v) {
            int kt2 = s * 2 + v;
            bhalf8 a[4], bb[4];
            #pragma unroll
            for (int i = 0; i < 4; i++) a[i] = *(const bhalf8*)&Ys[((kt2 * 4 + i) * 64 + lane) * 8];
            #pragma unroll
            for (int j = 0; j < 4; j++) bb[j] = *(const bhalf8*)&Bs[((v * 16) + wid * 4 + j) * 512 + lane * 8];
            #pragma unroll
            for (int i = 0; i < 4; i++)
                #pragma unroll
                for (int j = 0; j < 4; j++) acc2[i][j] = mfma16(a[i], bb[j], acc2[i][j]);
        }
        __syncthreads();
    }
    #pragma unroll
    for (int i = 0; i < 4; i++) {
        #pragma unroll
        for (int jf = 0; jf < 4; jf++) {
            int n = wid * 64 + jf * 16 + c;
            float bv = bn2[n];
            #pragma unroll
            for (int reg = 0; reg < 4; reg++) {
                int m = bm + i * 16 + r0 + reg;
                out[(size_t)m * 256 + n] = acc2[i][jf][reg] + bv;
            }
        }
    }
}

// ---------------------------------------------------------------------------
extern "C" void kernel_launch(void* const* d_in, const int* in_sizes, int n_in,
                              void* d_out, int out_size, void* d_ws, size_t ws_size,
                              hipStream_t stream)
{
    const int*   alias  = (const int*)  d_in[0];
    const float* A      = (const float*)d_in[1];
    const int*   items  = (const int*)  d_in[2];
    const int*   mask   = (const int*)  d_in[3];
    const float* emb    = (const float*)d_in[4];
    const float* W_ein  = (const float*)d_in[5];
    const float* b_ein  = (const float*)d_in[6];
    const float* W_eout = (const float*)d_in[7];
    const float* b_eout = (const float*)d_in[8];
    const float* b_iah  = (const float*)d_in[9];
    const float* b_oah  = (const float*)d_in[10];
    const float* W_i    = (const float*)d_in[11];
    const float* b_i    = (const float*)d_in[12];
    const float* W_h    = (const float*)d_in[13];
    const float* b_h    = (const float*)d_in[14];
    const float* W1     = (const float*)d_in[15];
    const float* b1     = (const float*)d_in[16];
    const float* W2     = (const float*)d_in[17];
    const float* b2     = (const float*)d_in[18];
    const float* W3     = (const float*)d_in[19];
    const float* Wn1    = (const float*)d_in[20];
    const float* bn1    = (const float*)d_in[21];
    const float* Wn2    = (const float*)d_in[22];
    const float* bn2    = (const float*)d_in[23];
    float* out = (float*)d_out;
    (void)in_sizes; (void)n_in; (void)out_size; (void)ws_size;

    char* w = (char*)d_ws;
    unsigned short* hidden_pk = (unsigned short*)(w);                 // 16,777,216
    unsigned short* inp_pk    = (unsigned short*)(w + 50331648);      // 33,554,432
    unsigned short* newh_bf   = (unsigned short*)(w + 83886080);      // 16,777,216
    unsigned short* Wio_pk    = (unsigned short*)(w + 100663296);     //    262,144
    unsigned short* Wg_pk     = (unsigned short*)(w + 100925440);     //  1,179,648
    unsigned short* W2pk      = (unsigned short*)(w + 102105088);     //    131,072
    unsigned short* Wn1pk     = (unsigned short*)(w + 102236160);     //    262,144
    unsigned short* Wn2pk     = (unsigned short*)(w + 102498304);     //    131,072
    unsigned short* ht_bf     = (unsigned short*)(w + 102629376);     //    262,144
    unsigned short* a_bf      = (unsigned short*)(w + 102891520);     //    262,144

    pack_all   <<<7936, 256, 0, stream>>>(W_ein, W_eout, W_i, W_h, W2, Wn1, Wn2,
                                          items, emb,
                                          Wio_pk, Wg_pk, W2pk, Wn1pk, Wn2pk, hidden_pk);
    gemm_hioadj<<<dim3(256, 4), 256, 0, stream>>>(hidden_pk, Wio_pk, b_ein, b_eout,
                                                  A, b_iah, b_oah, inp_pk);
    gru_mfma   <<<dim3(256, 4), 256, 0, stream>>>(inp_pk, hidden_pk, Wg_pk, b_i, b_h, newh_bf);
    attn_fused <<<512, 256, 0, stream>>>(newh_bf, alias, mask, W1, b1, b2, W3, W2pk, ht_bf, a_bf);
    mlp_fused  <<<8, 256, 0, stream>>>(a_bf, ht_bf, Wn1pk, bn1, Wn2pk, bn2, out);
}